// Round 10
// baseline (575.602 us; speedup 1.0000x reference)
//
#include <hip/hip_runtime.h>
#include <hip/hip_fp16.h>

#define LQ    42875      // 35^3 tokens
#define NTOK  343
#define X1SZ  2058000    // LQ*48

// ws float offsets. QKV fp16 path (r5 proved ws >= 65.3 MB).
#define OFF_MEAN 0        // 48 channel sums
#define OFF_QKV  36928    // fp16 [s][w][i][288]: 24,696,000 halves; O aliases Q cols
#define OFF_WF   12500000 // packed fp16 MFMA B-frags: w1/w2 (10752 u4) + qkv (6912 u4)
#define OFF_RPB  12600000 // rpbh [s*6+h][343][344] fp16 (stride 344 = 16B rows)
#define OFF_MASKH 13400000 // maskh [w][343][344] fp16 (stride 344)
#define QKV_BYTES_NEEDED 56100000ull
#define MASKH_BYTES_NEEDED 83100000ull   // 53.6MB + 29.5MB padded maskh

typedef _Float16 f16x8 __attribute__((ext_vector_type(8)));
typedef float f32x4 __attribute__((ext_vector_type(4)));
union B128 { uint4 u; f16x8 h; _Float16 e[8]; };
union U2H { unsigned u; __half2 h; };

__device__ __forceinline__ int src_index(int w, int i, int& par) {
  int gi = w / 25, gj = (w / 5) % 5, gk = w % 5;
  int ph = i / 49, pw = (i / 7) % 7, pt = i % 7;
  int hs = gi * 7 + ph + 3; if (hs >= 35) hs -= 35;
  int wd = gj * 7 + pw + 3; if (wd >= 35) wd -= 35;
  int td = gk * 7 + pt + 3; if (td >= 35) td -= 35;
  par = ((hs / 7) + (wd / 7) + (td / 7)) & 1;
  return (hs * 35 + wd) * 35 + td;
}

// K0b: pack weights into fp16 MFMA B-fragment layout (once, tiny).
// r15: k_init folded in (block 0 zeroes the gate meanbuf).
__global__ __launch_bounds__(256) void k_pack(
    const float* __restrict__ w1a, const float* __restrict__ w1b,
    const float* __restrict__ w2a, const float* __restrict__ w2b,
    const float* __restrict__ qwa, const float* __restrict__ qwb,
    float* __restrict__ ws) {
  if (blockIdx.x == 0 && threadIdx.x < 49) ws[OFF_MEAN + threadIdx.x] = 0.f;
  int idx = blockIdx.x * 256 + threadIdx.x;
  if (idx >= 17664) return;
  uint4* WFB = (uint4*)(ws + OFF_WF);
  unsigned short h[8];
  uint4* dst;
  if (idx < 10752) {
    int s = idx / 5376, r = idx - s * 5376;
    uint4* WF = WFB + (size_t)s * 5376;
    if (r < 3072) {
      int jn = r / 128, t = r - jn * 128, kk = t / 64, lane = t - kk * 64;
      int q = lane >> 4, n = lane & 15;
      const float* w1 = s ? w1b : w1a;
      int j = jn * 16 + n;
#pragma unroll
      for (int e = 0; e < 8; e++) {
        int k = kk * 32 + q * 8 + e;
        float v = (k < 48) ? w1[k * 384 + j] : 0.f;
        h[e] = __half_as_ushort(__float2half(v));
      }
    } else {
      int rr = r - 3072;
      int kt = rr / 192, t = rr - kt * 192, cn = t / 64, lane = t - cn * 64;
      int q = lane >> 4, n = lane & 15;
      const float* w2 = s ? w2b : w2a;
      int c = cn * 16 + n;
#pragma unroll
      for (int e = 0; e < 8; e++) {
        int j = kt * 32 + q * 8 + e;
        h[e] = __half_as_ushort(__float2half(w2[j * 48 + c]));
      }
    }
    dst = WF + r;
  } else {
    int idx2 = idx - 10752;
    int s = idx2 / 3456, r = idx2 - s * 3456;
    int jn = r / 192, t = r - jn * 192, kk = t / 64, lane = t - kk * 64;
    int q = lane >> 4, n = lane & 15;
    const float* qw = s ? qwb : qwa;
    int j = jn * 16 + n;
#pragma unroll
    for (int e = 0; e < 8; e++) {
      int k = kk * 32 + q * 8 + e;   // always < 96
      h[e] = __half_as_ushort(__float2half(qw[k * 288 + j]));
    }
    dst = WFB + 10752 + (size_t)s * 3456 + r;
  }
  uint4 u;
  u.x = (unsigned)h[0] | ((unsigned)h[1] << 16);
  u.y = (unsigned)h[2] | ((unsigned)h[3] << 16);
  u.z = (unsigned)h[4] | ((unsigned)h[5] << 16);
  u.w = (unsigned)h[6] | ((unsigned)h[7] << 16);
  *dst = u;
}

// K0c (r13): rpb -> rpbh[s*6+h][343][344] fp16, 16B-aligned rows.
__global__ __launch_bounds__(256) void k_rpb(
    const float* __restrict__ rpa, const float* __restrict__ rpbp,
    float* __restrict__ ws) {
  int sh = blockIdx.y;           // s*6+h
  int s = sh / 6, h = sh - s * 6;
  int idx = blockIdx.x * 256 + threadIdx.x;
  if (idx >= 117649) return;
  int ir = idx / 343, j = idx - ir * 343;
  int bi = (ir / 49) * 169 + ((ir / 7) % 7) * 13 + (ir % 7) + 1098;
  int bj = (j / 49) * 169 + ((j / 7) % 7) * 13 + (j % 7);
  const float* rp = s ? rpbp : rpa;
  ((__half*)(ws + OFF_RPB))[(size_t)sh * 117992 + ir * 344 + j] =
      __float2half(rp[(bi - bj) * 6 + h]);
}

// K0d (r14): mask fp32 -> fp16 padded rows, vectorized.
__global__ __launch_bounds__(256) void k_maskh(
    const float* __restrict__ mask, __half* __restrict__ mh) {
  int idx = blockIdx.x * 256 + threadIdx.x;
  if (idx >= 42875 * 86) return;
  int row = idx / 86, c = (idx - row * 86) * 4;
  const float* src = mask + (size_t)row * 343 + c;
  float v0 = src[0];
  float v1 = (c + 1 < 343) ? src[1] : 0.f;
  float v2 = (c + 2 < 343) ? src[2] : 0.f;
  float v3 = (c + 3 < 343) ? src[3] : 0.f;
  U2H a, b;
  a.h = __floats2half2_rn(v0, v1);
  b.h = __floats2half2_rn(v2, v3);
  uint2 o; o.x = a.u; o.y = b.u;
  *(uint2*)(mh + (size_t)row * 344 + c) = o;
}

// K_qkv (r10): MFMA QKV, k_mlp-style. 4 waves x 16 tokens.
__global__ __launch_bounds__(256) void k_qkv(
    const float* __restrict__ xa, const float* __restrict__ xb,
    const float* __restrict__ ga, const float* __restrict__ ba,
    const float* __restrict__ gb, const float* __restrict__ bb,
    const float* __restrict__ qba, const float* __restrict__ qbb,
    const float* __restrict__ ws, __half* __restrict__ qkvh) {
  __shared__ uint4 LDSB[2368];  // 4 waves x 592 u4 (Xf 192 u4, tile 16x37 u4)
  int s = blockIdx.z;
  int tid = threadIdx.x;
  int wid = tid >> 6, lane = tid & 63;
  int quad = lane >> 4, n15 = lane & 15;
  uint4* WR = LDSB + wid * 592;
  _Float16* th = (_Float16*)WR;
  int tbase = blockIdx.x * 64 + wid * 16;

  if (lane < 32) {
    int tt = lane & 15, which = lane >> 4;
    int t = tbase + tt;
    float v[48];
    bool wr = false, dup = false;
    if (t < LQ) {
      int w = t / 343, i = t - w * 343;
      int par; int src = src_index(w, i, par);
      const float* xr; const float* G; const float* B;
      bool doit;
      if (which == 0) { xr = (s ? xb : xa) + src * 48; G = s ? gb : ga; B = s ? bb : ba; doit = true; dup = (par == 1); }
      else            { xr = (s ? xa : xb) + src * 48; G = s ? ga : gb; B = s ? ba : bb; doit = (par == 0); }
      if (doit) {
        float sm = 0.f, sq = 0.f;
#pragma unroll
        for (int q4 = 0; q4 < 12; q4++) {
          float4 tv = ((const float4*)xr)[q4];
          v[4 * q4] = tv.x; v[4 * q4 + 1] = tv.y; v[4 * q4 + 2] = tv.z; v[4 * q4 + 3] = tv.w;
          sm += tv.x + tv.y + tv.z + tv.w;
          sq += tv.x * tv.x + tv.y * tv.y + tv.z * tv.z + tv.w * tv.w;
        }
        float m = sm * (1.f / 48.f);
        float r = rsqrtf(sq * (1.f / 48.f) - m * m + 1e-5f);
#pragma unroll
        for (int k = 0; k < 48; k++) v[k] = (v[k] - m) * r * G[k] + B[k];
        wr = true;
      }
    } else if (which == 0) {
#pragma unroll
      for (int k = 0; k < 48; k++) v[k] = 0.f;
      wr = true; dup = true;
    }
    if (wr) {
#pragma unroll
      for (int c6 = 0; c6 < 6; c6++) {
        unsigned short h[8];
#pragma unroll
        for (int e = 0; e < 8; e++) h[e] = __half_as_ushort(__float2half(v[c6 * 8 + e]));
        uint4 u;
        u.x = (unsigned)h[0] | ((unsigned)h[1] << 16);
        u.y = (unsigned)h[2] | ((unsigned)h[3] << 16);
        u.z = (unsigned)h[4] | ((unsigned)h[5] << 16);
        u.w = (unsigned)h[6] | ((unsigned)h[7] << 16);
        WR[(which * 6 + c6) * 16 + tt] = u;
        if (dup) WR[(6 + c6) * 16 + tt] = u;
      }
    }
  }
  // wave-internal LDS dep (writers lanes 0-31, readers same wave): lgkmcnt.

  B128 ax0, ax1, ax2;
  ax0.u = WR[(0 + quad) * 16 + n15];   // k 0..31
  ax1.u = WR[(4 + quad) * 16 + n15];   // k 32..63
  ax2.u = WR[(8 + quad) * 16 + n15];   // k 64..95

  const uint4* QF = (const uint4*)(ws + OFF_WF) + 10752 + (size_t)s * 3456;
  const float* QB = s ? qbb : qba;
  const f32x4 ZC = {0.f, 0.f, 0.f, 0.f};

  for (int jn = 0; jn < 18; jn++) {
    B128 b0, b1, b2;
    b0.u = QF[(jn * 3 + 0) * 64 + lane];
    b1.u = QF[(jn * 3 + 1) * 64 + lane];
    b2.u = QF[(jn * 3 + 2) * 64 + lane];
    f32x4 c = __builtin_amdgcn_mfma_f32_16x16x32_f16(ax0.h, b0.h, ZC, 0, 0, 0);
    c = __builtin_amdgcn_mfma_f32_16x16x32_f16(ax1.h, b1.h, c, 0, 0, 0);
    c = __builtin_amdgcn_mfma_f32_16x16x32_f16(ax2.h, b2.h, c, 0, 0, 0);
    float bias = QB[jn * 16 + n15];
    float scale = (jn < 6) ? 0.25f : 1.0f;
#pragma unroll
    for (int r = 0; r < 4; r++)
      th[(quad * 4 + r) * 296 + jn * 16 + n15] = (_Float16)((c[r] + bias) * scale);
  }
  // coalesced store: 16 rows x 36 uint4 (576B runs)
  for (int e = lane; e < 576; e += 64) {
    int row = e / 36, cc = e - row * 36;
    int t = tbase + row;
    if (t < LQ)
      ((uint4*)qkvh)[(size_t)(s * LQ + t) * 36 + cc] = WR[row * 37 + cc];
  }
}

// K1 (r16): register-P swapped-QK attention, VGPR-trimmed for occupancy.
// r9 counters: VGPR 108 -> 16 waves/CU ceiling, occupancy 19%, latency-
// bound on bias loads. Fixes: (1) bias prefetch kept as packed half2 sums
// (4 unsigned vs 16 floats; unpack at exp), (2) rpb row = mask row +
// SGPR-resident invariant delta (one VGPR pointer), (3) launch_bounds
// (256,6) -> VGPR<=84 -> 24 waves/CU ceiling. Spill tripwire: WRITE_SIZE
// must stay ~16.5MB.
template <bool H16>
__global__ __launch_bounds__(256, 6) void k_attn(
    const __half* __restrict__ rpbmat,
    const void* __restrict__ maskp, __half* __restrict__ qkvh) {
  int bid = blockIdx.x;
  int xcd = bid & 7, q8 = bid >> 3;
  int u = q8 / 12, inst = q8 - u * 12;
  int w = u * 8 + xcd;
  if (w >= 125) return;
  int s = inst & 1, h = inst >> 1;

  // FRAG (uint4): Kf[0..703], Vf[704..1407]
  __shared__ uint4 FRAG[1408];
  uint4* Kf4 = FRAG;
  uint4* Vf4 = FRAG + 704;
  _Float16* Vfh = (_Float16*)(FRAG + 704);

  int tid = threadIdx.x;
  const uint4 Z4 = {0u, 0u, 0u, 0u};
  for (int e = tid; e < 1408; e += 256) FRAG[e] = Z4;  // zero K/V tails
  __syncthreads();

  size_t wbase = (size_t)((s * 125 + w) * NTOK) * 288;
  for (int i = tid; i < NTOK; i += 256) {
    const uint4* row = (const uint4*)(qkvh + wbase + (size_t)i * 288) + (h * 2);
    uint4 k0 = row[12], k1 = row[13];    // K (+96 halves)
    B128 v0, v1; v0.u = row[24]; v1.u = row[25];  // V (+192 halves)
    int n = i & 15, it = i >> 4;
    Kf4[it * 32 + n] = k0;
    Kf4[it * 32 + 16 + n] = k1;
    // permuted V: uint4 [t5][qq][d] element ee = V[token][d], where
    // token i&31 -> (qq,ee): il<16: qq=il>>2, ee=il&3; else qq=(il-16)>>2,
    // ee=4+((il-16)&3). Matches register-P kslot order.
    int il = i & 31, t5 = i >> 5;
    int qq, ee;
    if (il < 16) { qq = il >> 2; ee = il & 3; }
    else { qq = (il - 16) >> 2; ee = 4 + ((il - 16) & 3); }
    int vb = (t5 * 64 + qq * 16) * 8 + ee;
#pragma unroll
    for (int d = 0; d < 8; d++) {
      Vfh[vb + d * 8] = v0.e[d];
      Vfh[vb + (d + 8) * 8] = v1.e[d];
    }
  }
  __syncthreads();

  int wid = tid >> 6, lane = tid & 63;
  int quad = lane >> 4, n15 = lane & 15;
  const f32x4 ZC = {0.f, 0.f, 0.f, 0.f};
  __half* obh = qkvh;  // O aliases Q cols of this block's slice
  int ja0 = quad * 4;

  // invariant row-delta: rpb row = mask row + rdelta (both stride 344)
  const __half* mbase;
  const float* mbasef = nullptr;
  ptrdiff_t rdelta = 0;
  {
    const __half* rb = rpbmat + (size_t)(s * 6 + h) * 117992;
    if constexpr (H16) {
      mbase = (const __half*)maskp + (size_t)w * 343 * 344;
      rdelta = rb - mbase;
    } else {
      mbasef = (const float*)maskp + (size_t)w * 343 * 343;
      mbase = rb;   // fallback: mbase points at rpb rows directly
    }
  }

  for (int it = wid; it < 22; it += 4) {
    int i0 = it * 16;
    int irow = i0 + n15; if (irow > 342) irow = 342;
    const __half* mrow = mbase + (size_t)irow * 344;

    // Q fragment direct from global (B-operand; same data layout as A).
    B128 qbits;
    int qtok = i0 + n15;
    if (quad < 2 && qtok < NTOK)
      qbits.u = *((const uint4*)(qkvh + wbase + (size_t)qtok * 288) + h * 2 + (quad & 1));
    else
      qbits.u = Z4;
    f32x4 acc = ZC;
    float ls = 0.f;

    unsigned bcur[4], bnxt[4];   // packed half2 of (mask+rpb), 8 j-values
    auto loadb = [&](int jt, unsigned* b) {
      if constexpr (H16) {
        const __half* mp = mrow + jt * 32 + ja0;
        const __half* rp2 = mp + rdelta;
        uint2 ma = *(const uint2*)mp;
        uint2 mb = *(const uint2*)(mp + 16);
        uint2 ra = *(const uint2*)rp2;
        uint2 rb = *(const uint2*)(rp2 + 16);
        U2H x, y;
        x.u = ma.x; y.u = ra.x; x.h = __hadd2(x.h, y.h); b[0] = x.u;
        x.u = ma.y; y.u = ra.y; x.h = __hadd2(x.h, y.h); b[1] = x.u;
        x.u = mb.x; y.u = rb.x; x.h = __hadd2(x.h, y.h); b[2] = x.u;
        x.u = mb.y; y.u = rb.y; x.h = __hadd2(x.h, y.h); b[3] = x.u;
      } else {
        const float* mp = mbasef + (size_t)irow * 343 + jt * 32 + ja0;
        const __half* rp2 = mrow + jt * 32 + ja0;   // mrow = rpb row here
        U2H x;
#pragma unroll
        for (int c = 0; c < 2; c++) {
          float f0 = mp[c * 16 + 0] + __half2float(rp2[c * 16 + 0]);
          float f1 = mp[c * 16 + 1] + __half2float(rp2[c * 16 + 1]);
          float f2 = mp[c * 16 + 2] + __half2float(rp2[c * 16 + 2]);
          float f3 = mp[c * 16 + 3] + __half2float(rp2[c * 16 + 3]);
          x.h = __floats2half2_rn(f0, f1); b[c * 2] = x.u;
          x.h = __floats2half2_rn(f2, f3); b[c * 2 + 1] = x.u;
        }
      }
    };
    loadb(0, bcur);

    for (int j32 = 0; j32 < 11; j32++) {
      if (j32 < 10) loadb(j32 + 1, bnxt);
      B128 kb0, kb1;
      kb0.u = Kf4[(j32 * 2) * 32 + ((quad & 1) << 4) + n15];
      kb1.u = Kf4[(j32 * 2 + 1) * 32 + ((quad & 1) << 4) + n15];
      if (quad >= 2) { kb0.u = Z4; kb1.u = Z4; }
      // swapped: C[row = k-local (quad*4+r)][col = q-token (n15)]
      f32x4 s0 = __builtin_amdgcn_mfma_f32_16x16x32_f16(kb0.h, qbits.h, ZC, 0, 0, 0);
      f32x4 s1 = __builtin_amdgcn_mfma_f32_16x16x32_f16(kb1.h, qbits.h, ZC, 0, 0, 0);
      bool last = (j32 == 10);
      U2H t0, t1;
      float2 f0, f1;
      float p0[4], p1[4];
      t0.u = bcur[0]; f0 = __half22float2(t0.h);
      t1.u = bcur[1]; f1 = __half22float2(t1.h);
      // scores bounded (|qk|<~1, |mask|<~6): exp safe w/o max-subtract
      p0[0] = __expf(s0[0] + f0.x);
      p0[1] = __expf(s0[1] + f0.y);
      p0[2] = __expf(s0[2] + f1.x);
      p0[3] = __expf(s0[3] + f1.y);
      t0.u = bcur[2]; f0 = __half22float2(t0.h);
      t1.u = bcur[3]; f1 = __half22float2(t1.h);
      float b10 = f0.x, b11 = f0.y, b12 = f1.x, b13 = f1.y;
      if (last) {   // j = 336 + quad*4+r exceeds 342 when quad*4+r >= 7
        if (quad * 4 + 0 >= 7) b10 = -1e30f;
        if (quad * 4 + 1 >= 7) b11 = -1e30f;
        if (quad * 4 + 2 >= 7) b12 = -1e30f;
        if (quad * 4 + 3 >= 7) b13 = -1e30f;
      }
      p1[0] = __expf(s1[0] + b10);
      p1[1] = __expf(s1[1] + b11);
      p1[2] = __expf(s1[2] + b12);
      p1[3] = __expf(s1[3] + b13);
      ls += ((p0[0] + p0[1]) + (p0[2] + p0[3])) + ((p1[0] + p1[1]) + (p1[2] + p1[3]));
      // register P -> PV A-frag directly (same lane owns both sides)
      U2H c0, c1, c2, c3;
      c0.h = __floats2half2_rn(p0[0], p0[1]);
      c1.h = __floats2half2_rn(p0[2], p0[3]);
      c2.h = __floats2half2_rn(p1[0], p1[1]);
      c3.h = __floats2half2_rn(p1[2], p1[3]);
      B128 pa;
      pa.u.x = c0.u; pa.u.y = c1.u; pa.u.z = c2.u; pa.u.w = c3.u;
      B128 vbits; vbits.u = Vf4[j32 * 64 + lane];
      acc = __builtin_amdgcn_mfma_f32_16x16x32_f16(pa.h, vbits.h, acc, 0, 0, 0);
#pragma unroll
      for (int e = 0; e < 4; e++) bcur[e] = bnxt[e];
    }
    // softmax denom: lane holds partial for i=i0+n15; sum across quads.
    ls += __shfl_xor(ls, 16);
    ls += __shfl_xor(ls, 32);
#pragma unroll
    for (int r = 0; r < 4; r++) {
      float lr = __shfl(ls, quad * 4 + r);   // full sum for row i0+quad*4+r
      int ir = i0 + quad * 4 + r;
      if (ir < 343)
        obh[wbase + (size_t)ir * 288 + h * 16 + n15] = __float2half(acc[r] * (1.f / lr));
    }
  }
}

// K1b: proj (fp16 O rows) + inverse shuffle scatter + residual -> d_out
__global__ __launch_bounds__(384) void k_proj(
    const __half* __restrict__ qkvh,
    const float* __restrict__ xa0, const float* __restrict__ xb0,
    const float* __restrict__ pwa, const float* __restrict__ pba,
    const float* __restrict__ pwb, const float* __restrict__ pbb,
    float* __restrict__ out) {
  int sw = blockIdx.x; int s = sw / 125, w = sw - s * 125;
  int i = threadIdx.x;
  if (i >= NTOK) return;
  const float* Wt = s ? pwb : pwa;
  const float* Bi = s ? pbb : pba;
  const uint4* orow = (const uint4*)(qkvh + (size_t)((s * 125 + w) * NTOK + i) * 288);
  float acc[48];
#pragma unroll
  for (int c = 0; c < 48; c++) acc[c] = 0.f;
#pragma unroll
  for (int k8 = 0; k8 < 12; k8++) {
    B128 ov; ov.u = orow[k8];
#pragma unroll
    for (int e = 0; e < 8; e++) {
      float x = (float)ov.e[e];
      const float* wr = Wt + (k8 * 8 + e) * 96;
#pragma unroll
      for (int c = 0; c < 48; c++) acc[c] = fmaf(x, wr[c], acc[c]);
    }
  }
  int par; int src = src_index(w, i, par);
  const float* x0 = (s ? xb0 : xa0) + src * 48;
  float* dst = out + s * X1SZ + src * 48;
#pragma unroll
  for (int q = 0; q < 12; q++) {
    float4 xv = ((const float4*)x0)[q];
    float4 o;
    o.x = xv.x + acc[4 * q + 0] + Bi[4 * q + 0];
    o.y = xv.y + acc[4 * q + 1] + Bi[4 * q + 1];
    o.z = xv.z + acc[4 * q + 2] + Bi[4 * q + 2];
    o.w = xv.w + acc[4 * q + 3] + Bi[4 * q + 3];
    ((float4*)dst)[q] = o;
  }
}

// K2 (r9): MFMA MLP. Block = 64 tokens, 4 waves, wave = 16 tokens.
__global__ __launch_bounds__(256) void k_mlp(
    const float* __restrict__ g2a, const float* __restrict__ b2a,
    const float* __restrict__ g2b, const float* __restrict__ b2b,
    const float* __restrict__ fb1a, const float* __restrict__ fb2a,
    const float* __restrict__ fb1b, const float* __restrict__ fb2b,
    float* __restrict__ out, float* __restrict__ ws) {
  __shared__ uint4 Xf[512];      // [wave(4)][kc(8)][n(16)] A-frag chunks
  __shared__ uint4 tbu[320];     // per-wave 16 rows x 40 halves (80 uint4)
  __shared__ float red[48];
  int s = blockIdx.z;
  int tid = threadIdx.x;
  int wid = tid >> 6, lane = tid & 63;
  int quad = lane >> 4, n15 = lane & 15;
  if (tid < 48) red[tid] = 0.f;
  __syncthreads();

  const float* B1 = s ? fb1b : fb1a;
  const float* B2 = s ? fb2b : fb2a;
  const uint4* W1F = (const uint4*)(ws + OFF_WF) + (size_t)s * 5376;
  const uint4* W2F = W1F + 3072;
  int tbase = blockIdx.x * 64 + wid * 16;
  float* outs = out + (size_t)s * X1SZ;

  // LN stage: lanes 0-15 of each wave handle the wave's 16 tokens.
  if (lane < 16) {
    int t = tbase + lane;
    float v[48];
    if (t < LQ) {
      const float* row = outs + (size_t)t * 48;
      float sm = 0.f, sq = 0.f;
#pragma unroll
      for (int q4 = 0; q4 < 12; q4++) {
        float4 tv = ((const float4*)row)[q4];
        v[4 * q4] = tv.x; v[4 * q4 + 1] = tv.y; v[4 * q4 + 2] = tv.z; v[4 * q4 + 3] = tv.w;
        sm += tv.x + tv.y + tv.z + tv.w;
        sq += tv.x * tv.x + tv.y * tv.y + tv.z * tv.z + tv.w * tv.w;
      }
      float m = sm * (1.f / 48.f);
      float r = rsqrtf(sq * (1.f / 48.f) - m * m + 1e-5f);
      const float* G = s ? g2b : g2a;
      const float* B = s ? b2b : b2a;
#pragma unroll
      for (int k = 0; k < 48; k++) v[k] = (v[k] - m) * r * G[k] + B[k];
    } else {
#pragma unroll
      for (int k = 0; k < 48; k++) v[k] = 0.f;
    }
#pragma unroll
    for (int kc = 0; kc < 8; kc++) {
      uint4 u = {0u, 0u, 0u, 0u};
      if (kc < 6) {
        unsigned short h[8];
#pragma unroll
        for (int e = 0; e < 8; e++) h[e] = __half_as_ushort(__float2half(v[kc * 8 + e]));
        u.x = (unsigned)h[0] | ((unsigned)h[1] << 16);
        u.y = (unsigned)h[2] | ((unsigned)h[3] << 16);
        u.z = (unsigned)h[4] | ((unsigned)h[5] << 16);
        u.w = (unsigned)h[6] | ((unsigned)h[7] << 16);
      }
      Xf[wid * 128 + kc * 16 + lane] = u;
    }
  }
  // wave-internal LDS dep: compiler orders via lgkmcnt; no barrier needed.

  _Float16* mytb = (_Float16*)(tbu + wid * 80);
  const uint4* mytb4 = tbu + wid * 80;
  const f32x4 ZC = {0.f, 0.f, 0.f, 0.f};
  f32x4 oacc[3] = {ZC, ZC, ZC};
  B128 ax0, ax1;
  ax0.u = Xf[wid * 128 + quad * 16 + n15];        // k 0..31
  ax1.u = Xf[wid * 128 + (4 + quad) * 16 + n15];  // k 32..63 (zero-padded)

  for (int kt = 0; kt < 12; kt++) {
    int jn0 = kt * 2, jn1 = jn0 + 1;
    B128 w0, w1, w2, w3;
    w0.u = W1F[jn0 * 128 + lane];
    w1.u = W1F[jn0 * 128 + 64 + lane];
    w2.u = W1F[jn1 * 128 + lane];
    w3.u = W1F[jn1 * 128 + 64 + lane];
    f32x4 a0 = __builtin_amdgcn_mfma_f32_16x16x32_f16(ax0.h, w0.h, ZC, 0, 0, 0);
    a0 = __builtin_amdgcn_mfma_f32_16x16x32_f16(ax1.h, w1.h, a0, 0, 0, 0);
    f32x4 a1 = __builtin_amdgcn_mfma_f32_16x16x32_f16(ax0.h, w2.h, ZC, 0, 0, 0);
    a1 = __builtin_amdgcn_mfma_f32_16x16x32_f16(ax1.h, w3.h, a1, 0, 0, 0);
    float bz0 = B1[jn0 * 16 + n15], bz1 = B1[jn1 * 16 + n15];
    // gelu + transpose-store: C-tile lane holds col n15, rows quad*4+r.
#pragma unroll
    for (int r = 0; r < 4; r++) {
      float h0 = a0[r] + bz0;
      h0 = 0.5f * h0 * (1.f + erff(h0 * 0.70710678118654752f));
      float h1 = a1[r] + bz1;
      h1 = 0.5f * h1 * (1.f + erff(h1 * 0.70710678118654752f));
      int rowb = (quad * 4 + r) * 40;
      mytb[rowb + n15] = (_Float16)h0;
      mytb[rowb + 16 + n15] = (_Float16)h1;
    }
    // fc2 A-frag read-back: token n15, local hid quad*8..+7
    B128 pa; pa.u = mytb4[n15 * 5 + quad];
    B128 c0, c1, c2;
    c0.u = W2F[kt * 192 + lane];
    c1.u = W2F[kt * 192 + 64 + lane];
    c2.u = W2F[kt * 192 + 128 + lane];
    oacc[0] = __builtin_amdgcn_mfma_f32_16x16x32_f16(pa.h, c0.h, oacc[0], 0, 0, 0);
    oacc[1] = __builtin_amdgcn_mfma_f32_16x16x32_f16(pa.h, c1.h, oacc[1], 0, 0, 0);
    oacc[2] = __builtin_amdgcn_mfma_f32_16x16x32_f16(pa.h, c2.h, oacc[2], 0, 0, 0);
  }

  // epilogue: residual + b2, store, gate partials
  float b2v[3];
#pragma unroll
  for (int cn = 0; cn < 3; cn++) b2v[cn] = B2[cn * 16 + n15];
  float gsum[3] = {0.f, 0.f, 0.f};
#pragma unroll
  for (int r = 0; r < 4; r++) {
    int t = tbase + quad * 4 + r;
    bool val = t < LQ;
    float* orow = outs + (size_t)(val ? t : 0) * 48;
#pragma unroll
    for (int cn = 0; cn < 3; cn++) {
      float fin = 0.f;
      if (val) {
        fin = orow[cn * 16 + n15] + oacc[cn][r] + b2v[cn];
        orow[cn * 16 + n15] = fin;
      }
      gsum[cn] += fin;
    }
  }
  if (s == 0) {
#pragma unroll
    for (int cn = 0; cn < 3; cn++) {
      float v = gsum[cn];
      v += __shfl_xor(v, 16); v += __shfl_xor(v, 32);
      if (quad == 0) atomicAdd(&red[cn * 16 + n15], v);
    }
  }
  __syncthreads();
  if (s == 0 && tid < 48) atomicAdd(ws + OFF_MEAN + tid, red[tid]);
}

// K4 (r15): gate scalar computed in-block (k_gate launch removed), then
// out_a += g * out_b.
__global__ __launch_bounds__(256) void k_gadd(
    float* __restrict__ out, const float* __restrict__ ws_mean,
    const float* __restrict__ gw1, const float* __restrict__ gw2,
    const float* __restrict__ gb2) {
  __shared__ float gs;
  int tid = threadIdx.x;
  if (tid < 64) {
    float t = 0.f;
    if (tid < 12) {
      for (int c = 0; c < 48; c++)
        t = fmaf(ws_mean[c] * (1.f / (float)LQ), gw1[c * 12 + tid], t);
      t = fmaxf(t, 0.f) * gw2[tid];
    }
    for (int off = 32; off > 0; off >>= 1) t += __shfl_down(t, off);
    if (tid == 0) gs = 1.f / (1.f + __expf(-(t + gb2[0])));
  }
  __syncthreads();
  float gv = gs;
  int i = blockIdx.x * 256 + tid;
  if (i >= X1SZ / 4) return;
  float4* a = (float4*)out;
  const float4* b = (const float4*)(out + X1SZ);
  float4 x = a[i], y = b[i];
  x.x = fmaf(gv, y.x, x.x);
  x.y = fmaf(gv, y.y, x.y);
  x.z = fmaf(gv, y.z, x.z);
  x.w = fmaf(gv, y.w, x.w);
  a[i] = x;
}

extern "C" void kernel_launch(void* const* d_in, const int* in_sizes, int n_in,
                              void* d_out, int out_size, void* d_ws, size_t ws_size,
                              hipStream_t stream) {
  const float* xa    = (const float*)d_in[0];
  const float* xb    = (const float*)d_in[1];
  const float* mask  = (const float*)d_in[2];
  const float* n1ag  = (const float*)d_in[3];
  const float* n1ab  = (const float*)d_in[4];
  const float* n1bg  = (const float*)d_in[5];
  const float* n1bb  = (const float*)d_in[6];
  const float* rpba  = (const float*)d_in[7];
  const float* qkvwa = (const float*)d_in[8];
  const float* qkvba = (const float*)d_in[9];
  const float* pwa   = (const float*)d_in[10];
  const float* pba   = (const float*)d_in[11];
  const float* rpbb  = (const float*)d_in[12];
  const float* qkvwb = (const float*)d_in[13];
  const float* qkvbb = (const float*)d_in[14];
  const float* pwb   = (const float*)d_in[15];
  const float* pbb   = (const float*)d_in[16];
  const float* n2ag  = (const float*)d_in[17];
  const float* n2ab  = (const float*)d_in[18];
  const float* n2bg  = (const float*)d_in[19];
  const float* n2bb  = (const float*)d_in[20];
  const float* w1a   = (const float*)d_in[21];
  const float* fb1a  = (const float*)d_in[22];
  const float* w2a   = (const float*)d_in[23];
  const float* fb2a  = (const float*)d_in[24];
  const float* w1b   = (const float*)d_in[25];
  const float* fb1b  = (const float*)d_in[26];
  const float* w2b   = (const float*)d_in[27];
  const float* fb2b  = (const float*)d_in[28];
  const float* gw1   = (const float*)d_in[29];
  const float* gw2   = (const float*)d_in[30];
  const float* gb2   = (const float*)d_in[31];
  float* ws  = (float*)d_ws;
  float* out = (float*)d_out;

  if (ws_size < QKV_BYTES_NEEDED) return;  // r5 proved ws >= 65.3 MB
  __half* qkvh = (__half*)(ws + OFF_QKV);
  bool bigmask = ws_size >= MASKH_BYTES_NEEDED;

  hipLaunchKernelGGL(k_pack, dim3(69), dim3(256), 0, stream,
                     w1a, w1b, w2a, w2b, qkvwa, qkvwb, ws);
  hipLaunchKernelGGL(k_rpb, dim3(460, 12), dim3(256), 0, stream,
                     rpba, rpbb, ws);
  if (bigmask)
    hipLaunchKernelGGL(k_maskh, dim3(14405), dim3(256), 0, stream,
                       mask, (__half*)(ws + OFF_MASKH));
  hipLaunchKernelGGL(k_qkv, dim3(670, 1, 2), dim3(256), 0, stream,
                     xa, xb, n1ag, n1ab, n1bg, n1bb,
                     qkvba, qkvbb, ws, qkvh);
  if (bigmask)
    hipLaunchKernelGGL((k_attn<true>), dim3(1536), dim3(256), 0, stream,
                       (const __half*)(ws + OFF_RPB),
                       (const void*)(ws + OFF_MASKH), qkvh);
  else
    hipLaunchKernelGGL((k_attn<false>), dim3(1536), dim3(256), 0, stream,
                       (const __half*)(ws + OFF_RPB), (const void*)mask, qkvh);
  hipLaunchKernelGGL(k_proj, dim3(250), dim3(384), 0, stream,
                     qkvh, xa, xb, pwa, pba, pwb, pbb, out);
  hipLaunchKernelGGL(k_mlp, dim3(670, 1, 2), dim3(256), 0, stream,
                     n2ag, n2ab, n2bg, n2bb,
                     fb1a, fb2a, fb1b, fb2b, out, ws);
  hipLaunchKernelGGL(k_gadd, dim3(2011), dim3(256), 0, stream,
                     out, ws + OFF_MEAN, gw1, gw2, gb2);
}

// Round 11
// 375.957 us; speedup vs baseline: 1.5310x; 1.5310x over previous
//
#include <hip/hip_runtime.h>
#include <hip/hip_fp16.h>

#define LQ    42875      // 35^3 tokens
#define NTOK  343
#define X1SZ  2058000    // LQ*48

// ws float offsets. QKV fp16 path (r5 proved ws >= 65.3 MB).
#define OFF_MEAN 0        // 48 channel sums
#define OFF_QKV  36928    // fp16 [s][w][i][288]: 24,696,000 halves; O aliases Q cols
#define OFF_WF   12500000 // packed fp16 MFMA B-frags: w1/w2 + qkv + proj (18816 u4)
#define OFF_RPB  12600000 // rpbh [s*6+h][343][344] fp16 (stride 344 = 16B rows)
#define OFF_MASKH 13400000 // maskh [w][343][344] fp16 (stride 344)
#define QKV_BYTES_NEEDED 56100000ull
#define MASKH_BYTES_NEEDED 83100000ull   // 53.6MB + 29.5MB padded maskh

typedef _Float16 f16x8 __attribute__((ext_vector_type(8)));
typedef float f32x4 __attribute__((ext_vector_type(4)));
union B128 { uint4 u; f16x8 h; _Float16 e[8]; };
union U2H { unsigned u; __half2 h; };

__device__ __forceinline__ int src_index(int w, int i, int& par) {
  int gi = w / 25, gj = (w / 5) % 5, gk = w % 5;
  int ph = i / 49, pw = (i / 7) % 7, pt = i % 7;
  int hs = gi * 7 + ph + 3; if (hs >= 35) hs -= 35;
  int wd = gj * 7 + pw + 3; if (wd >= 35) wd -= 35;
  int td = gk * 7 + pt + 3; if (td >= 35) td -= 35;
  par = ((hs / 7) + (wd / 7) + (td / 7)) & 1;
  return (hs * 35 + wd) * 35 + td;
}

// K0b: pack weights into fp16 MFMA B-fragment layout (once, tiny).
// r17: + proj_w B-frags (cols 0..47 only — reference drops cols 48..95):
// [17664 + s*576 + jn*192 + kk*64 + lane], lane(q,n) e = pw[(kk*32+q*8+e)*96
// + jn*16+n]. Block 0 zeroes the gate meanbuf.
__global__ __launch_bounds__(256) void k_pack(
    const float* __restrict__ w1a, const float* __restrict__ w1b,
    const float* __restrict__ w2a, const float* __restrict__ w2b,
    const float* __restrict__ qwa, const float* __restrict__ qwb,
    const float* __restrict__ pwa, const float* __restrict__ pwb,
    float* __restrict__ ws) {
  if (blockIdx.x == 0 && threadIdx.x < 49) ws[OFF_MEAN + threadIdx.x] = 0.f;
  int idx = blockIdx.x * 256 + threadIdx.x;
  if (idx >= 18816) return;
  uint4* WFB = (uint4*)(ws + OFF_WF);
  unsigned short h[8];
  uint4* dst;
  if (idx < 10752) {
    int s = idx / 5376, r = idx - s * 5376;
    uint4* WF = WFB + (size_t)s * 5376;
    if (r < 3072) {
      int jn = r / 128, t = r - jn * 128, kk = t / 64, lane = t - kk * 64;
      int q = lane >> 4, n = lane & 15;
      const float* w1 = s ? w1b : w1a;
      int j = jn * 16 + n;
#pragma unroll
      for (int e = 0; e < 8; e++) {
        int k = kk * 32 + q * 8 + e;
        float v = (k < 48) ? w1[k * 384 + j] : 0.f;
        h[e] = __half_as_ushort(__float2half(v));
      }
    } else {
      int rr = r - 3072;
      int kt = rr / 192, t = rr - kt * 192, cn = t / 64, lane = t - cn * 64;
      int q = lane >> 4, n = lane & 15;
      const float* w2 = s ? w2b : w2a;
      int c = cn * 16 + n;
#pragma unroll
      for (int e = 0; e < 8; e++) {
        int j = kt * 32 + q * 8 + e;
        h[e] = __half_as_ushort(__float2half(w2[j * 48 + c]));
      }
    }
    dst = WF + r;
  } else if (idx < 17664) {
    int idx2 = idx - 10752;
    int s = idx2 / 3456, r = idx2 - s * 3456;
    int jn = r / 192, t = r - jn * 192, kk = t / 64, lane = t - kk * 64;
    int q = lane >> 4, n = lane & 15;
    const float* qw = s ? qwb : qwa;
    int j = jn * 16 + n;
#pragma unroll
    for (int e = 0; e < 8; e++) {
      int k = kk * 32 + q * 8 + e;   // always < 96
      h[e] = __half_as_ushort(__float2half(qw[k * 288 + j]));
    }
    dst = WFB + 10752 + (size_t)s * 3456 + r;
  } else {
    int idx3 = idx - 17664;
    int s = idx3 / 576, r = idx3 - s * 576;
    int jn = r / 192, t = r - jn * 192, kk = t / 64, lane = t - kk * 64;
    int q = lane >> 4, n = lane & 15;
    const float* pw = s ? pwb : pwa;
    int c = jn * 16 + n;   // < 48
#pragma unroll
    for (int e = 0; e < 8; e++) {
      int k = kk * 32 + q * 8 + e;   // < 96
      h[e] = __half_as_ushort(__float2half(pw[k * 96 + c]));
    }
    dst = WFB + 17664 + (size_t)s * 576 + r;
  }
  uint4 u;
  u.x = (unsigned)h[0] | ((unsigned)h[1] << 16);
  u.y = (unsigned)h[2] | ((unsigned)h[3] << 16);
  u.z = (unsigned)h[4] | ((unsigned)h[5] << 16);
  u.w = (unsigned)h[6] | ((unsigned)h[7] << 16);
  *dst = u;
}

// K0c (r13): rpb -> rpbh[s*6+h][343][344] fp16, 16B-aligned rows.
__global__ __launch_bounds__(256) void k_rpb(
    const float* __restrict__ rpa, const float* __restrict__ rpbp,
    float* __restrict__ ws) {
  int sh = blockIdx.y;           // s*6+h
  int s = sh / 6, h = sh - s * 6;
  int idx = blockIdx.x * 256 + threadIdx.x;
  if (idx >= 117649) return;
  int ir = idx / 343, j = idx - ir * 343;
  int bi = (ir / 49) * 169 + ((ir / 7) % 7) * 13 + (ir % 7) + 1098;
  int bj = (j / 49) * 169 + ((j / 7) % 7) * 13 + (j % 7);
  const float* rp = s ? rpbp : rpa;
  ((__half*)(ws + OFF_RPB))[(size_t)sh * 117992 + ir * 344 + j] =
      __float2half(rp[(bi - bj) * 6 + h]);
}

// K0d (r14): mask fp32 -> fp16 padded rows, vectorized.
__global__ __launch_bounds__(256) void k_maskh(
    const float* __restrict__ mask, __half* __restrict__ mh) {
  int idx = blockIdx.x * 256 + threadIdx.x;
  if (idx >= 42875 * 86) return;
  int row = idx / 86, c = (idx - row * 86) * 4;
  const float* src = mask + (size_t)row * 343 + c;
  float v0 = src[0];
  float v1 = (c + 1 < 343) ? src[1] : 0.f;
  float v2 = (c + 2 < 343) ? src[2] : 0.f;
  float v3 = (c + 3 < 343) ? src[3] : 0.f;
  U2H a, b;
  a.h = __floats2half2_rn(v0, v1);
  b.h = __floats2half2_rn(v2, v3);
  uint2 o; o.x = a.u; o.y = b.u;
  *(uint2*)(mh + (size_t)row * 344 + c) = o;
}

// K_qkv (r10): MFMA QKV, k_mlp-style. 4 waves x 16 tokens.
__global__ __launch_bounds__(256) void k_qkv(
    const float* __restrict__ xa, const float* __restrict__ xb,
    const float* __restrict__ ga, const float* __restrict__ ba,
    const float* __restrict__ gb, const float* __restrict__ bb,
    const float* __restrict__ qba, const float* __restrict__ qbb,
    const float* __restrict__ ws, __half* __restrict__ qkvh) {
  __shared__ uint4 LDSB[2368];  // 4 waves x 592 u4 (Xf 192 u4, tile 16x37 u4)
  int s = blockIdx.z;
  int tid = threadIdx.x;
  int wid = tid >> 6, lane = tid & 63;
  int quad = lane >> 4, n15 = lane & 15;
  uint4* WR = LDSB + wid * 592;
  _Float16* th = (_Float16*)WR;
  int tbase = blockIdx.x * 64 + wid * 16;

  if (lane < 32) {
    int tt = lane & 15, which = lane >> 4;
    int t = tbase + tt;
    float v[48];
    bool wr = false, dup = false;
    if (t < LQ) {
      int w = t / 343, i = t - w * 343;
      int par; int src = src_index(w, i, par);
      const float* xr; const float* G; const float* B;
      bool doit;
      if (which == 0) { xr = (s ? xb : xa) + src * 48; G = s ? gb : ga; B = s ? bb : ba; doit = true; dup = (par == 1); }
      else            { xr = (s ? xa : xb) + src * 48; G = s ? ga : gb; B = s ? ba : bb; doit = (par == 0); }
      if (doit) {
        float sm = 0.f, sq = 0.f;
#pragma unroll
        for (int q4 = 0; q4 < 12; q4++) {
          float4 tv = ((const float4*)xr)[q4];
          v[4 * q4] = tv.x; v[4 * q4 + 1] = tv.y; v[4 * q4 + 2] = tv.z; v[4 * q4 + 3] = tv.w;
          sm += tv.x + tv.y + tv.z + tv.w;
          sq += tv.x * tv.x + tv.y * tv.y + tv.z * tv.z + tv.w * tv.w;
        }
        float m = sm * (1.f / 48.f);
        float r = rsqrtf(sq * (1.f / 48.f) - m * m + 1e-5f);
#pragma unroll
        for (int k = 0; k < 48; k++) v[k] = (v[k] - m) * r * G[k] + B[k];
        wr = true;
      }
    } else if (which == 0) {
#pragma unroll
      for (int k = 0; k < 48; k++) v[k] = 0.f;
      wr = true; dup = true;
    }
    if (wr) {
#pragma unroll
      for (int c6 = 0; c6 < 6; c6++) {
        unsigned short h[8];
#pragma unroll
        for (int e = 0; e < 8; e++) h[e] = __half_as_ushort(__float2half(v[c6 * 8 + e]));
        uint4 u;
        u.x = (unsigned)h[0] | ((unsigned)h[1] << 16);
        u.y = (unsigned)h[2] | ((unsigned)h[3] << 16);
        u.z = (unsigned)h[4] | ((unsigned)h[5] << 16);
        u.w = (unsigned)h[6] | ((unsigned)h[7] << 16);
        WR[(which * 6 + c6) * 16 + tt] = u;
        if (dup) WR[(6 + c6) * 16 + tt] = u;
      }
    }
  }
  // wave-internal LDS dep (writers lanes 0-31, readers same wave): lgkmcnt.

  B128 ax0, ax1, ax2;
  ax0.u = WR[(0 + quad) * 16 + n15];   // k 0..31
  ax1.u = WR[(4 + quad) * 16 + n15];   // k 32..63
  ax2.u = WR[(8 + quad) * 16 + n15];   // k 64..95

  const uint4* QF = (const uint4*)(ws + OFF_WF) + 10752 + (size_t)s * 3456;
  const float* QB = s ? qbb : qba;
  const f32x4 ZC = {0.f, 0.f, 0.f, 0.f};

  for (int jn = 0; jn < 18; jn++) {
    B128 b0, b1, b2;
    b0.u = QF[(jn * 3 + 0) * 64 + lane];
    b1.u = QF[(jn * 3 + 1) * 64 + lane];
    b2.u = QF[(jn * 3 + 2) * 64 + lane];
    f32x4 c = __builtin_amdgcn_mfma_f32_16x16x32_f16(ax0.h, b0.h, ZC, 0, 0, 0);
    c = __builtin_amdgcn_mfma_f32_16x16x32_f16(ax1.h, b1.h, c, 0, 0, 0);
    c = __builtin_amdgcn_mfma_f32_16x16x32_f16(ax2.h, b2.h, c, 0, 0, 0);
    float bias = QB[jn * 16 + n15];
    float scale = (jn < 6) ? 0.25f : 1.0f;
#pragma unroll
    for (int r = 0; r < 4; r++)
      th[(quad * 4 + r) * 296 + jn * 16 + n15] = (_Float16)((c[r] + bias) * scale);
  }
  // coalesced store: 16 rows x 36 uint4 (576B runs)
  for (int e = lane; e < 576; e += 64) {
    int row = e / 36, cc = e - row * 36;
    int t = tbase + row;
    if (t < LQ)
      ((uint4*)qkvh)[(size_t)(s * LQ + t) * 36 + cc] = WR[row * 37 + cc];
  }
}

// K1 (r15/r17): register-P swapped-QK attention — EXACT r9 version (107us,
// VGPR 108, no spill). r10's (256,6) bound forced VGPR 40 -> 553MB spill
// traffic, 2.3x slower. Natural footprint is ~108; occupancy quantum (m69:
// steps at 64/128) means trimming to ~100 buys nothing. Do not bound.
template <bool H16>
__global__ __launch_bounds__(256) void k_attn(
    const __half* __restrict__ rpbmat,
    const void* __restrict__ maskp, __half* __restrict__ qkvh) {
  int bid = blockIdx.x;
  int xcd = bid & 7, q8 = bid >> 3;
  int u = q8 / 12, inst = q8 - u * 12;
  int w = u * 8 + xcd;
  if (w >= 125) return;
  int s = inst & 1, h = inst >> 1;

  // FRAG (uint4): Kf[0..703], Vf[704..1407]
  __shared__ uint4 FRAG[1408];
  uint4* Kf4 = FRAG;
  uint4* Vf4 = FRAG + 704;
  _Float16* Vfh = (_Float16*)(FRAG + 704);

  int tid = threadIdx.x;
  const uint4 Z4 = {0u, 0u, 0u, 0u};
  for (int e = tid; e < 1408; e += 256) FRAG[e] = Z4;  // zero K/V tails
  __syncthreads();

  size_t wbase = (size_t)((s * 125 + w) * NTOK) * 288;
  for (int i = tid; i < NTOK; i += 256) {
    const uint4* row = (const uint4*)(qkvh + wbase + (size_t)i * 288) + (h * 2);
    uint4 k0 = row[12], k1 = row[13];    // K (+96 halves)
    B128 v0, v1; v0.u = row[24]; v1.u = row[25];  // V (+192 halves)
    int n = i & 15, it = i >> 4;
    Kf4[it * 32 + n] = k0;
    Kf4[it * 32 + 16 + n] = k1;
    // permuted V: matches register-P kslot order (see r15 header).
    int il = i & 31, t5 = i >> 5;
    int qq, ee;
    if (il < 16) { qq = il >> 2; ee = il & 3; }
    else { qq = (il - 16) >> 2; ee = 4 + ((il - 16) & 3); }
    int vb = (t5 * 64 + qq * 16) * 8 + ee;
#pragma unroll
    for (int d = 0; d < 8; d++) {
      Vfh[vb + d * 8] = v0.e[d];
      Vfh[vb + (d + 8) * 8] = v1.e[d];
    }
  }
  __syncthreads();

  int wid = tid >> 6, lane = tid & 63;
  int quad = lane >> 4, n15 = lane & 15;
  const f32x4 ZC = {0.f, 0.f, 0.f, 0.f};
  __half* obh = qkvh;  // O aliases Q cols of this block's slice
  const __half* rbase = rpbmat + (size_t)(s * 6 + h) * 117992;
  int ja0 = quad * 4;

  for (int it = wid; it < 22; it += 4) {
    int i0 = it * 16;
    int irow = i0 + n15; if (irow > 342) irow = 342;
    const __half* rrow = rbase + (size_t)irow * 344;
    const __half* mrow = nullptr; const float* mrowf = nullptr;
    if constexpr (H16) mrow = (const __half*)maskp + ((size_t)w * 343 + irow) * 344;
    else mrowf = (const float*)maskp + ((size_t)w * 343 + irow) * 343;

    // Q fragment direct from global (B-operand; same data layout as A).
    B128 qbits;
    int qtok = i0 + n15;
    if (quad < 2 && qtok < NTOK)
      qbits.u = *((const uint4*)(qkvh + wbase + (size_t)qtok * 288) + h * 2 + (quad & 1));
    else
      qbits.u = Z4;
    f32x4 acc = ZC;
    float ls = 0.f;

    float bcur[8], bnxt[8];
    auto loadb = [&](int jt, float* b) {
      if constexpr (H16) {
        const __half* mp = mrow + jt * 32 + ja0;
        const __half* rp2 = rrow + jt * 32 + ja0;
        uint2 ma = *(const uint2*)mp;
        uint2 mb = *(const uint2*)(mp + 16);
        uint2 ra = *(const uint2*)rp2;
        uint2 rb = *(const uint2*)(rp2 + 16);
        U2H x0, x1, x2, x3, y0, y1, y2, y3;
        x0.u = ma.x; x1.u = ma.y; x2.u = mb.x; x3.u = mb.y;
        y0.u = ra.x; y1.u = ra.y; y2.u = rb.x; y3.u = rb.y;
        float2 f;
        f = __half22float2(__hadd2(x0.h, y0.h)); b[0] = f.x; b[1] = f.y;
        f = __half22float2(__hadd2(x1.h, y1.h)); b[2] = f.x; b[3] = f.y;
        f = __half22float2(__hadd2(x2.h, y2.h)); b[4] = f.x; b[5] = f.y;
        f = __half22float2(__hadd2(x3.h, y3.h)); b[6] = f.x; b[7] = f.y;
      } else {
        const float* mp = mrowf + jt * 32 + ja0;
        const __half* rp2 = rrow + jt * 32 + ja0;
#pragma unroll
        for (int r = 0; r < 4; r++) {
          b[r] = mp[r] + __half2float(rp2[r]);
          b[4 + r] = mp[16 + r] + __half2float(rp2[16 + r]);
        }
      }
    };
    loadb(0, bcur);

    for (int j32 = 0; j32 < 11; j32++) {
      if (j32 < 10) loadb(j32 + 1, bnxt);
      B128 kb0, kb1;
      kb0.u = Kf4[(j32 * 2) * 32 + ((quad & 1) << 4) + n15];
      kb1.u = Kf4[(j32 * 2 + 1) * 32 + ((quad & 1) << 4) + n15];
      if (quad >= 2) { kb0.u = Z4; kb1.u = Z4; }
      // swapped: C[row = k-local (quad*4+r)][col = q-token (n15)]
      f32x4 s0 = __builtin_amdgcn_mfma_f32_16x16x32_f16(kb0.h, qbits.h, ZC, 0, 0, 0);
      f32x4 s1 = __builtin_amdgcn_mfma_f32_16x16x32_f16(kb1.h, qbits.h, ZC, 0, 0, 0);
      bool last = (j32 == 10);
      float p0[4], p1[4];
#pragma unroll
      for (int r = 0; r < 4; r++) {
        float b1 = bcur[4 + r];
        if (last && (quad * 4 + r) >= 7) b1 = -1e30f;
        // scores bounded (|qk|<~1, |mask|<~6): exp safe w/o max-subtract
        p0[r] = __expf(s0[r] + bcur[r]);
        p1[r] = __expf(s1[r] + b1);
        ls += p0[r] + p1[r];
      }
      // register P -> PV A-frag directly (same lane owns both sides)
      U2H c0, c1, c2, c3;
      c0.h = __floats2half2_rn(p0[0], p0[1]);
      c1.h = __floats2half2_rn(p0[2], p0[3]);
      c2.h = __floats2half2_rn(p1[0], p1[1]);
      c3.h = __floats2half2_rn(p1[2], p1[3]);
      B128 pa;
      pa.u.x = c0.u; pa.u.y = c1.u; pa.u.z = c2.u; pa.u.w = c3.u;
      B128 vbits; vbits.u = Vf4[j32 * 64 + lane];
      acc = __builtin_amdgcn_mfma_f32_16x16x32_f16(pa.h, vbits.h, acc, 0, 0, 0);
#pragma unroll
      for (int e = 0; e < 8; e++) bcur[e] = bnxt[e];
    }
    // softmax denom: lane holds partial for i=i0+n15; sum across quads.
    ls += __shfl_xor(ls, 16);
    ls += __shfl_xor(ls, 32);
#pragma unroll
    for (int r = 0; r < 4; r++) {
      float lr = __shfl(ls, quad * 4 + r);   // full sum for row i0+quad*4+r
      int ir = i0 + quad * 4 + r;
      if (ir < 343)
        obh[wbase + (size_t)ir * 288 + h * 16 + n15] = __float2half(acc[r] * (1.f / lr));
    }
  }
}

// K1b (r17): MFMA proj. Old k_proj was occupancy-starved (250 blocks =
// ~1 block/CU, 4608 serial FMAs/thread, est ~55us). Now k_mlp-style:
// grid (670,1,2) x 4 waves x 16 tokens; A-frags = contiguous fp16 O rows
// (cols 0..95 of qkvh row, 3 uint4/lane); B-frags = packed proj_w cols
// 0..47 (reference drops 48..95); 9 MFMAs; epilogue = inverse shuffle
// scatter + residual (16-lane 64B-coalesced runs).
__global__ __launch_bounds__(256) void k_proj(
    const __half* __restrict__ qkvh,
    const float* __restrict__ xa0, const float* __restrict__ xb0,
    const float* __restrict__ pba, const float* __restrict__ pbb,
    const float* __restrict__ ws, float* __restrict__ out) {
  int s = blockIdx.z;
  int tid = threadIdx.x;
  int wid = tid >> 6, lane = tid & 63;
  int quad = lane >> 4, n15 = lane & 15;
  int t0 = blockIdx.x * 64 + wid * 16;

  int tA = t0 + n15; if (tA >= LQ) tA = LQ - 1;   // clamp: garbage only
  const uint4* orow = (const uint4*)qkvh + (size_t)(s * LQ + tA) * 36;
  B128 a0, a1, a2;                                 // corrupts unwritten rows
  a0.u = orow[quad];        // k 0..31
  a1.u = orow[4 + quad];    // k 32..63
  a2.u = orow[8 + quad];    // k 64..95

  const uint4* PF = (const uint4*)(ws + OFF_WF) + 17664 + (size_t)s * 576;
  const float* Bi = s ? pbb : pba;
  const f32x4 ZC = {0.f, 0.f, 0.f, 0.f};
  f32x4 c[3];
#pragma unroll
  for (int jn = 0; jn < 3; jn++) {
    B128 b0, b1, b2;
    b0.u = PF[(jn * 3 + 0) * 64 + lane];
    b1.u = PF[(jn * 3 + 1) * 64 + lane];
    b2.u = PF[(jn * 3 + 2) * 64 + lane];
    f32x4 cc = __builtin_amdgcn_mfma_f32_16x16x32_f16(a0.h, b0.h, ZC, 0, 0, 0);
    cc = __builtin_amdgcn_mfma_f32_16x16x32_f16(a1.h, b1.h, cc, 0, 0, 0);
    cc = __builtin_amdgcn_mfma_f32_16x16x32_f16(a2.h, b2.h, cc, 0, 0, 0);
    c[jn] = cc;
  }
  float bias[3];
#pragma unroll
  for (int jn = 0; jn < 3; jn++) bias[jn] = Bi[jn * 16 + n15];
#pragma unroll
  for (int r = 0; r < 4; r++) {
    int t = t0 + quad * 4 + r;
    if (t >= LQ) continue;
    int w = t / 343, i = t - w * 343;
    int par; int src = src_index(w, i, par);
    const float* x0 = (s ? xb0 : xa0) + (size_t)src * 48;
    float* dst = out + (size_t)s * X1SZ + (size_t)src * 48;
#pragma unroll
    for (int jn = 0; jn < 3; jn++) {
      int col = jn * 16 + n15;
      dst[col] = x0[col] + c[jn][r] + bias[jn];
    }
  }
}

// K2 (r9): MFMA MLP. Block = 64 tokens, 4 waves, wave = 16 tokens.
__global__ __launch_bounds__(256) void k_mlp(
    const float* __restrict__ g2a, const float* __restrict__ b2a,
    const float* __restrict__ g2b, const float* __restrict__ b2b,
    const float* __restrict__ fb1a, const float* __restrict__ fb2a,
    const float* __restrict__ fb1b, const float* __restrict__ fb2b,
    float* __restrict__ out, float* __restrict__ ws) {
  __shared__ uint4 Xf[512];      // [wave(4)][kc(8)][n(16)] A-frag chunks
  __shared__ uint4 tbu[320];     // per-wave 16 rows x 40 halves (80 uint4)
  __shared__ float red[48];
  int s = blockIdx.z;
  int tid = threadIdx.x;
  int wid = tid >> 6, lane = tid & 63;
  int quad = lane >> 4, n15 = lane & 15;
  if (tid < 48) red[tid] = 0.f;
  __syncthreads();

  const float* B1 = s ? fb1b : fb1a;
  const float* B2 = s ? fb2b : fb2a;
  const uint4* W1F = (const uint4*)(ws + OFF_WF) + (size_t)s * 5376;
  const uint4* W2F = W1F + 3072;
  int tbase = blockIdx.x * 64 + wid * 16;
  float* outs = out + (size_t)s * X1SZ;

  // LN stage: lanes 0-15 of each wave handle the wave's 16 tokens.
  if (lane < 16) {
    int t = tbase + lane;
    float v[48];
    if (t < LQ) {
      const float* row = outs + (size_t)t * 48;
      float sm = 0.f, sq = 0.f;
#pragma unroll
      for (int q4 = 0; q4 < 12; q4++) {
        float4 tv = ((const float4*)row)[q4];
        v[4 * q4] = tv.x; v[4 * q4 + 1] = tv.y; v[4 * q4 + 2] = tv.z; v[4 * q4 + 3] = tv.w;
        sm += tv.x + tv.y + tv.z + tv.w;
        sq += tv.x * tv.x + tv.y * tv.y + tv.z * tv.z + tv.w * tv.w;
      }
      float m = sm * (1.f / 48.f);
      float r = rsqrtf(sq * (1.f / 48.f) - m * m + 1e-5f);
      const float* G = s ? g2b : g2a;
      const float* B = s ? b2b : b2a;
#pragma unroll
      for (int k = 0; k < 48; k++) v[k] = (v[k] - m) * r * G[k] + B[k];
    } else {
#pragma unroll
      for (int k = 0; k < 48; k++) v[k] = 0.f;
    }
#pragma unroll
    for (int kc = 0; kc < 8; kc++) {
      uint4 u = {0u, 0u, 0u, 0u};
      if (kc < 6) {
        unsigned short h[8];
#pragma unroll
        for (int e = 0; e < 8; e++) h[e] = __half_as_ushort(__float2half(v[kc * 8 + e]));
        u.x = (unsigned)h[0] | ((unsigned)h[1] << 16);
        u.y = (unsigned)h[2] | ((unsigned)h[3] << 16);
        u.z = (unsigned)h[4] | ((unsigned)h[5] << 16);
        u.w = (unsigned)h[6] | ((unsigned)h[7] << 16);
      }
      Xf[wid * 128 + kc * 16 + lane] = u;
    }
  }
  // wave-internal LDS dep: compiler orders via lgkmcnt; no barrier needed.

  _Float16* mytb = (_Float16*)(tbu + wid * 80);
  const uint4* mytb4 = tbu + wid * 80;
  const f32x4 ZC = {0.f, 0.f, 0.f, 0.f};
  f32x4 oacc[3] = {ZC, ZC, ZC};
  B128 ax0, ax1;
  ax0.u = Xf[wid * 128 + quad * 16 + n15];        // k 0..31
  ax1.u = Xf[wid * 128 + (4 + quad) * 16 + n15];  // k 32..63 (zero-padded)

  for (int kt = 0; kt < 12; kt++) {
    int jn0 = kt * 2, jn1 = jn0 + 1;
    B128 w0, w1, w2, w3;
    w0.u = W1F[jn0 * 128 + lane];
    w1.u = W1F[jn0 * 128 + 64 + lane];
    w2.u = W1F[jn1 * 128 + lane];
    w3.u = W1F[jn1 * 128 + 64 + lane];
    f32x4 a0 = __builtin_amdgcn_mfma_f32_16x16x32_f16(ax0.h, w0.h, ZC, 0, 0, 0);
    a0 = __builtin_amdgcn_mfma_f32_16x16x32_f16(ax1.h, w1.h, a0, 0, 0, 0);
    f32x4 a1 = __builtin_amdgcn_mfma_f32_16x16x32_f16(ax0.h, w2.h, ZC, 0, 0, 0);
    a1 = __builtin_amdgcn_mfma_f32_16x16x32_f16(ax1.h, w3.h, a1, 0, 0, 0);
    float bz0 = B1[jn0 * 16 + n15], bz1 = B1[jn1 * 16 + n15];
    // gelu + transpose-store: C-tile lane holds col n15, rows quad*4+r.
#pragma unroll
    for (int r = 0; r < 4; r++) {
      float h0 = a0[r] + bz0;
      h0 = 0.5f * h0 * (1.f + erff(h0 * 0.70710678118654752f));
      float h1 = a1[r] + bz1;
      h1 = 0.5f * h1 * (1.f + erff(h1 * 0.70710678118654752f));
      int rowb = (quad * 4 + r) * 40;
      mytb[rowb + n15] = (_Float16)h0;
      mytb[rowb + 16 + n15] = (_Float16)h1;
    }
    // fc2 A-frag read-back: token n15, local hid quad*8..+7
    B128 pa; pa.u = mytb4[n15 * 5 + quad];
    B128 c0, c1, c2;
    c0.u = W2F[kt * 192 + lane];
    c1.u = W2F[kt * 192 + 64 + lane];
    c2.u = W2F[kt * 192 + 128 + lane];
    oacc[0] = __builtin_amdgcn_mfma_f32_16x16x32_f16(pa.h, c0.h, oacc[0], 0, 0, 0);
    oacc[1] = __builtin_amdgcn_mfma_f32_16x16x32_f16(pa.h, c1.h, oacc[1], 0, 0, 0);
    oacc[2] = __builtin_amdgcn_mfma_f32_16x16x32_f16(pa.h, c2.h, oacc[2], 0, 0, 0);
  }

  // epilogue: residual + b2, store, gate partials
  float b2v[3];
#pragma unroll
  for (int cn = 0; cn < 3; cn++) b2v[cn] = B2[cn * 16 + n15];
  float gsum[3] = {0.f, 0.f, 0.f};
#pragma unroll
  for (int r = 0; r < 4; r++) {
    int t = tbase + quad * 4 + r;
    bool val = t < LQ;
    float* orow = outs + (size_t)(val ? t : 0) * 48;
#pragma unroll
    for (int cn = 0; cn < 3; cn++) {
      float fin = 0.f;
      if (val) {
        fin = orow[cn * 16 + n15] + oacc[cn][r] + b2v[cn];
        orow[cn * 16 + n15] = fin;
      }
      gsum[cn] += fin;
    }
  }
  if (s == 0) {
#pragma unroll
    for (int cn = 0; cn < 3; cn++) {
      float v = gsum[cn];
      v += __shfl_xor(v, 16); v += __shfl_xor(v, 32);
      if (quad == 0) atomicAdd(&red[cn * 16 + n15], v);
    }
  }
  __syncthreads();
  if (s == 0 && tid < 48) atomicAdd(ws + OFF_MEAN + tid, red[tid]);
}

// K4 (r15): gate scalar computed in-block, then out_a += g * out_b.
__global__ __launch_bounds__(256) void k_gadd(
    float* __restrict__ out, const float* __restrict__ ws_mean,
    const float* __restrict__ gw1, const float* __restrict__ gw2,
    const float* __restrict__ gb2) {
  __shared__ float gs;
  int tid = threadIdx.x;
  if (tid < 64) {
    float t = 0.f;
    if (tid < 12) {
      for (int c = 0; c < 48; c++)
        t = fmaf(ws_mean[c] * (1.f / (float)LQ), gw1[c * 12 + tid], t);
      t = fmaxf(t, 0.f) * gw2[tid];
    }
    for (int off = 32; off > 0; off >>= 1) t += __shfl_down(t, off);
    if (tid == 0) gs = 1.f / (1.f + __expf(-(t + gb2[0])));
  }
  __syncthreads();
  float gv = gs;
  int i = blockIdx.x * 256 + tid;
  if (i >= X1SZ / 4) return;
  float4* a = (float4*)out;
  const float4* b = (const float4*)(out + X1SZ);
  float4 x = a[i], y = b[i];
  x.x = fmaf(gv, y.x, x.x);
  x.y = fmaf(gv, y.y, x.y);
  x.z = fmaf(gv, y.z, x.z);
  x.w = fmaf(gv, y.w, x.w);
  a[i] = x;
}

extern "C" void kernel_launch(void* const* d_in, const int* in_sizes, int n_in,
                              void* d_out, int out_size, void* d_ws, size_t ws_size,
                              hipStream_t stream) {
  const float* xa    = (const float*)d_in[0];
  const float* xb    = (const float*)d_in[1];
  const float* mask  = (const float*)d_in[2];
  const float* n1ag  = (const float*)d_in[3];
  const float* n1ab  = (const float*)d_in[4];
  const float* n1bg  = (const float*)d_in[5];
  const float* n1bb  = (const float*)d_in[6];
  const float* rpba  = (const float*)d_in[7];
  const float* qkvwa = (const float*)d_in[8];
  const float* qkvba = (const float*)d_in[9];
  const float* pwa   = (const float*)d_in[10];
  const float* pba   = (const float*)d_in[11];
  const float* rpbb  = (const float*)d_in[12];
  const float* qkvwb = (const float*)d_in[13];
  const float* qkvbb = (const float*)d_in[14];
  const float* pwb   = (const float*)d_in[15];
  const float* pbb   = (const float*)d_in[16];
  const float* n2ag  = (const float*)d_in[17];
  const float* n2ab  = (const float*)d_in[18];
  const float* n2bg  = (const float*)d_in[19];
  const float* n2bb  = (const float*)d_in[20];
  const float* w1a   = (const float*)d_in[21];
  const float* fb1a  = (const float*)d_in[22];
  const float* w2a   = (const float*)d_in[23];
  const float* fb2a  = (const float*)d_in[24];
  const float* w1b   = (const float*)d_in[25];
  const float* fb1b  = (const float*)d_in[26];
  const float* w2b   = (const float*)d_in[27];
  const float* fb2b  = (const float*)d_in[28];
  const float* gw1   = (const float*)d_in[29];
  const float* gw2   = (const float*)d_in[30];
  const float* gb2   = (const float*)d_in[31];
  float* ws  = (float*)d_ws;
  float* out = (float*)d_out;

  if (ws_size < QKV_BYTES_NEEDED) return;  // r5 proved ws >= 65.3 MB
  __half* qkvh = (__half*)(ws + OFF_QKV);
  bool bigmask = ws_size >= MASKH_BYTES_NEEDED;

  hipLaunchKernelGGL(k_pack, dim3(74), dim3(256), 0, stream,
                     w1a, w1b, w2a, w2b, qkvwa, qkvwb, pwa, pwb, ws);
  hipLaunchKernelGGL(k_rpb, dim3(460, 12), dim3(256), 0, stream,
                     rpba, rpbb, ws);
  if (bigmask)
    hipLaunchKernelGGL(k_maskh, dim3(14405), dim3(256), 0, stream,
                       mask, (__half*)(ws + OFF_MASKH));
  hipLaunchKernelGGL(k_qkv, dim3(670, 1, 2), dim3(256), 0, stream,
                     xa, xb, n1ag, n1ab, n1bg, n1bb,
                     qkvba, qkvbb, ws, qkvh);
  if (bigmask)
    hipLaunchKernelGGL((k_attn<true>), dim3(1536), dim3(256), 0, stream,
                       (const __half*)(ws + OFF_RPB),
                       (const void*)(ws + OFF_MASKH), qkvh);
  else
    hipLaunchKernelGGL((k_attn<false>), dim3(1536), dim3(256), 0, stream,
                       (const __half*)(ws + OFF_RPB), (const void*)mask, qkvh);
  hipLaunchKernelGGL(k_proj, dim3(670, 1, 2), dim3(256), 0, stream,
                     qkvh, xa, xb, pba, pbb, ws, out);
  hipLaunchKernelGGL(k_mlp, dim3(670, 1, 2), dim3(256), 0, stream,
                     n2ag, n2ab, n2bg, n2bb,
                     fb1a, fb2a, fb1b, fb2b, out, ws);
  hipLaunchKernelGGL(k_gadd, dim3(2011), dim3(256), 0, stream,
                     out, ws + OFF_MEAN, gw1, gw2, gb2);
}